// Round 1
// baseline (238.092 us; speedup 1.0000x reference)
//
#include <hip/hip_runtime.h>
#include <hip/hip_bf16.h>

typedef __hip_bfloat16 bf16;
typedef __attribute__((ext_vector_type(8))) short short8;
typedef __attribute__((ext_vector_type(4))) float f32x4;

#define NN 128
#define DD_ 64
#define HH_ 8
#define DH_ 64
#define DI_ 512
#define SS_ 5
#define MLPD 1024
#define SDI 2560
#define KS2 4
#define KCM 64

__device__ __forceinline__ float wave_sum64(float v) {
#pragma unroll
    for (int off = 32; off > 0; off >>= 1) v += __shfl_xor(v, off, 64);
    return v;
}

__device__ __forceinline__ unsigned short f2bf_u(float f) {
    unsigned u = __float_as_uint(f);
    u += 0x7FFF + ((u >> 16) & 1);
    return (unsigned short)(u >> 16);
}
__device__ __forceinline__ float bfu2f(unsigned short s) {
    return __uint_as_float(((unsigned)s) << 16);
}
__device__ __forceinline__ unsigned pk2(unsigned short a, unsigned short b) {
    return (unsigned)a | ((unsigned)b << 16);
}

// K1: fused LN + q/k + mlp1, column-chunked. grid(128 i, 4 ch), block(256).
__global__ __launch_bounds__(256) void k_front(
    const float* __restrict__ h, const float* __restrict__ ghi, const float* __restrict__ ghj,
    const float* __restrict__ Wq, const float* __restrict__ Wk,
    const float* __restrict__ Wv1, const float* __restrict__ bv1,
    const float* __restrict__ Wp1, const float* __restrict__ bp1,
    float* __restrict__ q, float* __restrict__ k,
    float* __restrict__ a1, float* __restrict__ p1) {
    int i = blockIdx.x, ch = blockIdx.y, t = threadIdx.x;
    int d = t & 63;
    __shared__ float hib[DD_], hjb[DD_];
    float x = h[i * DD_ + d];
    float s = wave_sum64(x);
    float s2 = wave_sum64(x * x);
    float m = s * (1.0f / DD_);
    float v = s2 * (1.0f / DD_) - m * m;
    float r = rsqrtf(v + 1e-5f);
    float xc = (x - m) * r;
    if (t < 64) { hib[d] = xc * ghi[d]; hjb[d] = xc * ghj[d]; }
    __syncthreads();
    {
        int c = ch * 128 + (t & 127);
        const float* W = (t < 128) ? Wq : Wk;
        const float* hb = (t < 128) ? hib : hjb;
        float a = 0.f;
#pragma unroll 8
        for (int dd = 0; dd < DD_; dd++) a += hb[dd] * W[dd * DI_ + c];
        float* dstqk = (t < 128) ? q : k;
        dstqk[i * DI_ + c] = a;
    }
    {
        int c = ch * 256 + t;
        float av = 0.f, ap = 0.f;
#pragma unroll 4
        for (int dd = 0; dd < DD_; dd++) {
            float hv = hjb[dd];
            av += hv * Wv1[dd * MLPD + c];
            ap += hv * Wp1[dd * MLPD + c];
        }
        float xv = av + bv1[c], xp = ap + bp1[c];
        a1[i * MLPD + c] = xv / (1.0f + expf(-xv));
        p1[i * MLPD + c] = xp / (1.0f + expf(-xp));
    }
}

// K_mid: fused mlp2 (blocks 0..319) + den (320..447) + simnum (448..959).
// All three depend only on k_front; one launch so they run concurrently.
__global__ __launch_bounds__(256) void k_mid(
    const float* __restrict__ a1, const float* __restrict__ p1,
    const float* __restrict__ Wv2, const float* __restrict__ Wp2,
    float* __restrict__ part,
    const float* __restrict__ tij, const float* __restrict__ Wev,
    const float* __restrict__ q, float* __restrict__ rsd,
    const float* __restrict__ k, float* __restrict__ sn) {
    __shared__ __align__(16) unsigned char smem[30720];
    int b = blockIdx.x, t = threadIdx.x;
    if (b < 320) {
        // ---- mlp2: split-K MFMA GEMM (hi/lo bf16 compensation)
        unsigned short (*Ahi)[40] = (unsigned short (*)[40])(smem);
        unsigned short (*Alo)[40] = (unsigned short (*)[40])(smem + 10240);
        unsigned short (*Bhi)[40] = (unsigned short (*)[40])(smem + 20480);
        unsigned short (*Blo)[40] = (unsigned short (*)[40])(smem + 25600);
        int ct = b % 80, ks = b / 80;
        int c0 = ct * 64;
        bool isp = c0 >= 2560;
        int c0l = c0 - (isp ? 2560 : 0);
        const float* __restrict__ src = isp ? p1 : a1;
        const float* __restrict__ W = isp ? Wp2 : Wv2;
        int kbase = ks * 256;
        int lane = t & 63, wv = t >> 6;
        int l15 = lane & 15, quad = lane >> 4;
        f32x4 acc[2][4];
#pragma unroll
        for (int mt = 0; mt < 2; mt++)
#pragma unroll
            for (int nt = 0; nt < 4; nt++) acc[mt][nt] = (f32x4){0.f, 0.f, 0.f, 0.f};
        int aj = t >> 1, ak = (t & 1) * 16;
        int bc = t & 63, bk = (t >> 6) * 8;
        for (int kc = 0; kc < 8; kc++) {
            int k0 = kbase + kc * 32;
            __syncthreads();
            {
                unsigned short h16[16], l16[16];
                const float* ap = &src[(size_t)aj * MLPD + k0 + ak];
#pragma unroll
                for (int e = 0; e < 16; e += 4) {
                    float4 v = *(const float4*)(ap + e);
                    float vv[4] = {v.x, v.y, v.z, v.w};
#pragma unroll
                    for (int z = 0; z < 4; z++) {
                        unsigned short hb = f2bf_u(vv[z]);
                        h16[e + z] = hb;
                        l16[e + z] = f2bf_u(vv[z] - bfu2f(hb));
                    }
                }
                *(uint4*)&Ahi[aj][ak] = make_uint4(pk2(h16[0], h16[1]), pk2(h16[2], h16[3]),
                                                   pk2(h16[4], h16[5]), pk2(h16[6], h16[7]));
                *(uint4*)&Ahi[aj][ak + 8] = make_uint4(pk2(h16[8], h16[9]), pk2(h16[10], h16[11]),
                                                       pk2(h16[12], h16[13]), pk2(h16[14], h16[15]));
                *(uint4*)&Alo[aj][ak] = make_uint4(pk2(l16[0], l16[1]), pk2(l16[2], l16[3]),
                                                   pk2(l16[4], l16[5]), pk2(l16[6], l16[7]));
                *(uint4*)&Alo[aj][ak + 8] = make_uint4(pk2(l16[8], l16[9]), pk2(l16[10], l16[11]),
                                                       pk2(l16[12], l16[13]), pk2(l16[14], l16[15]));
            }
            {
                unsigned short h8[8], l8[8];
#pragma unroll
                for (int e = 0; e < 8; e++) {
                    float v = W[(size_t)(k0 + bk + e) * SDI + c0l + bc];
                    unsigned short hb = f2bf_u(v);
                    h8[e] = hb;
                    l8[e] = f2bf_u(v - bfu2f(hb));
                }
                *(uint4*)&Bhi[bc][bk] = make_uint4(pk2(h8[0], h8[1]), pk2(h8[2], h8[3]),
                                                   pk2(h8[4], h8[5]), pk2(h8[6], h8[7]));
                *(uint4*)&Blo[bc][bk] = make_uint4(pk2(l8[0], l8[1]), pk2(l8[2], l8[3]),
                                                   pk2(l8[4], l8[5]), pk2(l8[6], l8[7]));
            }
            __syncthreads();
            int ko = quad * 8;
            short8 a_h0 = *(const short8*)&Ahi[(wv * 2 + 0) * 16 + l15][ko];
            short8 a_l0 = *(const short8*)&Alo[(wv * 2 + 0) * 16 + l15][ko];
            short8 a_h1 = *(const short8*)&Ahi[(wv * 2 + 1) * 16 + l15][ko];
            short8 a_l1 = *(const short8*)&Alo[(wv * 2 + 1) * 16 + l15][ko];
#pragma unroll
            for (int nt = 0; nt < 4; nt++) {
                short8 b_h = *(const short8*)&Bhi[nt * 16 + l15][ko];
                short8 b_l = *(const short8*)&Blo[nt * 16 + l15][ko];
                acc[0][nt] = __builtin_amdgcn_mfma_f32_16x16x32_bf16(a_h0, b_h, acc[0][nt], 0, 0, 0);
                acc[0][nt] = __builtin_amdgcn_mfma_f32_16x16x32_bf16(a_h0, b_l, acc[0][nt], 0, 0, 0);
                acc[0][nt] = __builtin_amdgcn_mfma_f32_16x16x32_bf16(a_l0, b_h, acc[0][nt], 0, 0, 0);
                acc[1][nt] = __builtin_amdgcn_mfma_f32_16x16x32_bf16(a_h1, b_h, acc[1][nt], 0, 0, 0);
                acc[1][nt] = __builtin_amdgcn_mfma_f32_16x16x32_bf16(a_h1, b_l, acc[1][nt], 0, 0, 0);
                acc[1][nt] = __builtin_amdgcn_mfma_f32_16x16x32_bf16(a_l1, b_h, acc[1][nt], 0, 0, 0);
            }
        }
#pragma unroll
        for (int mt = 0; mt < 2; mt++)
#pragma unroll
            for (int nt = 0; nt < 4; nt++)
#pragma unroll
                for (int r = 0; r < 4; r++) {
                    int j = (wv * 2 + mt) * 16 + quad * 4 + r;
                    int cc = c0 + nt * 16 + l15;
                    part[(size_t)ks * 655360 + (size_t)j * 5120 + cc] = acc[mt][nt][r];
                }
    } else if (b < 448) {
        // ---- den: T-sum + EV + rsd, whole row per block (256 threads)
        float* red = (float*)smem;           // 4*64
        float* Tl = (float*)(smem + 1024);   // 64
        float* ql = (float*)(smem + 1280);   // 512
        int i = b - 320;
        int c = t & 63, jw = t >> 6;
        float s = 0.f;
        for (int j = jw; j < NN; j += 4) s += tij[(size_t)(i * NN + j) * DD_ + c];
        red[jw * 64 + c] = s;
        ql[t] = q[i * DI_ + t];
        ql[t + 256] = q[i * DI_ + t + 256];
        __syncthreads();
        if (t < 64) Tl[t] = red[t] + red[64 + t] + red[128 + t] + red[192 + t];
        __syncthreads();
#pragma unroll
        for (int kx = 0; kx < 10; kx++) {
            int u = kx * 256 + t;
            float ev = 0.f;
#pragma unroll 8
            for (int cc = 0; cc < DD_; cc++) ev += Tl[cc] * Wev[(size_t)cc * SDI + u];
            float den = wave_sum64(ev * ql[u & 511]);
            if ((t & 63) == 0) {
                int g = u >> 6;
                int ss = g >> 3, hh = g & 7;
                rsd[i * 40 + hh * SS_ + ss] = 1.0f / den;
            }
        }
    } else {
        // ---- simnum: 2 heads per block (256 threads)
        float* qb = (float*)smem;  // 128
        int idx = b - 448;
        int i = idx & 127, yh = idx >> 7;
        if (t < 128) qb[t] = q[i * DI_ + yh * 128 + t];
        __syncthreads();
        int hh = yh * 2 + (t >> 7), j = t & 127;
        float a = 0.f;
        const float* kr = &k[(size_t)j * DI_ + hh * DH_];
        const float* qr = &qb[(t >> 7) * 64];
#pragma unroll 8
        for (int d = 0; d < DH_; d++) a += qr[d] * kr[d];
        sn[i * 1024 + hh * NN + j] = a;
    }
}

// K_mid2: fused VC (blocks 0..639) + M (640..1279). M-branch reduces the
// pav partials from `part` inline (kills the pav round trip and the
// post->M serialization).
__global__ __launch_bounds__(256) void k_mid2(
    const float* __restrict__ part, const float* __restrict__ bv2,
    const float* __restrict__ bp2, const float* __restrict__ Wc,
    const float* __restrict__ Wev, float* __restrict__ VC, float* __restrict__ M) {
    __shared__ __align__(16) unsigned char smem[38912];
    int b = blockIdx.x, t = threadIdx.x;
    if (b < 640) {
        // ---- VC: reduce partials + bias -> vals, then @ Wc per head block
        float* vlds = (float*)smem;  // 512
        int j = b & 127, s = b >> 7;
#pragma unroll
        for (int r = 0; r < 2; r++) {
            int tt = r * 256 + t;
            int e = s * 512 + tt;
            float sum = 0.f;
#pragma unroll
            for (int p = 0; p < KS2; p++) sum += part[(size_t)p * 655360 + (size_t)j * 5120 + e];
            vlds[tt] = sum + bv2[e];
        }
        __syncthreads();
#pragma unroll
        for (int r = 0; r < 2; r++) {
            int tt = r * 256 + t;
            int dd = tt & 63;
            int hbase = tt - dd;
            float acc = 0.f;
#pragma unroll 8
            for (int d2 = 0; d2 < DH_; d2++)
                acc += vlds[hbase + d2] * Wc[(size_t)(hbase + d2) * DD_ + dd];
            VC[(size_t)(j * SS_ + s) * DI_ + tt] = acc;
        }
    } else {
        // ---- M via MFMA hi/lo bf16 compensation (pav computed inline)
        int idx = b - 640;
        int j = idx & 127, s = idx >> 7;
        int lane = t & 63, w = t >> 6;
        float* P = (float*)smem;  // 512 floats = 2048B
        unsigned short (*Ahi)[72] = (unsigned short (*)[72])(smem + 2048);
        unsigned short (*Alo)[72] = (unsigned short (*)[72])(smem + 11264);
        unsigned short (*Bhi)[72] = (unsigned short (*)[72])(smem + 20480);
        unsigned short (*Blo)[72] = (unsigned short (*)[72])(smem + 29696);
        {
            int e = 2560 + s * 512 + t;
            float s0 = 0.f, s1 = 0.f;
#pragma unroll
            for (int p = 0; p < KS2; p++) {
                s0 += part[(size_t)p * 655360 + (size_t)j * 5120 + e];
                s1 += part[(size_t)p * 655360 + (size_t)j * 5120 + e + 256];
            }
            P[t] = s0 + bp2[s * 512 + t];
            P[t + 256] = s1 + bp2[s * 512 + t + 256];
        }
        f32x4 acc[4];
#pragma unroll
        for (int n = 0; n < 4; n++) acc[n] = (f32x4){0.f, 0.f, 0.f, 0.f};
        __syncthreads();
        for (int u0 = 0; u0 < DI_; u0 += KCM) {
            {
                int c = t >> 2, ug = (t & 3) * 16;
                const float* wevp = &Wev[(size_t)c * SDI + s * DI_ + u0 + ug];
                unsigned short ah[16], al[16];
#pragma unroll
                for (int e = 0; e < 16; e += 4) {
                    float4 wv = *(const float4*)(wevp + e);
                    float4 pv = *(const float4*)&P[u0 + ug + e];
                    float av[4] = {wv.x * pv.x, wv.y * pv.y, wv.z * pv.z, wv.w * pv.w};
#pragma unroll
                    for (int z = 0; z < 4; z++) {
                        unsigned short hh2 = f2bf_u(av[z]);
                        ah[e + z] = hh2;
                        al[e + z] = f2bf_u(av[z] - bfu2f(hh2));
                    }
                }
                *(uint4*)&Ahi[c][ug] = make_uint4(pk2(ah[0], ah[1]), pk2(ah[2], ah[3]),
                                                  pk2(ah[4], ah[5]), pk2(ah[6], ah[7]));
                *(uint4*)&Ahi[c][ug + 8] = make_uint4(pk2(ah[8], ah[9]), pk2(ah[10], ah[11]),
                                                      pk2(ah[12], ah[13]), pk2(ah[14], ah[15]));
                *(uint4*)&Alo[c][ug] = make_uint4(pk2(al[0], al[1]), pk2(al[2], al[3]),
                                                  pk2(al[4], al[5]), pk2(al[6], al[7]));
                *(uint4*)&Alo[c][ug + 8] = make_uint4(pk2(al[8], al[9]), pk2(al[10], al[11]),
                                                      pk2(al[12], al[13]), pk2(al[14], al[15]));
            }
            {
                int dd = t & 63, ub = (t >> 6) * 16;
                unsigned short bh[16], bl[16];
#pragma unroll
                for (int e = 0; e < 16; e++) {
                    float v = Wc[(size_t)(u0 + ub + e) * DD_ + dd];
                    unsigned short hh2 = f2bf_u(v);
                    bh[e] = hh2;
                    bl[e] = f2bf_u(v - bfu2f(hh2));
                }
                *(uint4*)&Bhi[dd][ub] = make_uint4(pk2(bh[0], bh[1]), pk2(bh[2], bh[3]),
                                                   pk2(bh[4], bh[5]), pk2(bh[6], bh[7]));
                *(uint4*)&Bhi[dd][ub + 8] = make_uint4(pk2(bh[8], bh[9]), pk2(bh[10], bh[11]),
                                                       pk2(bh[12], bh[13]), pk2(bh[14], bh[15]));
                *(uint4*)&Blo[dd][ub] = make_uint4(pk2(bl[0], bl[1]), pk2(bl[2], bl[3]),
                                                   pk2(bl[4], bl[5]), pk2(bl[6], bl[7]));
                *(uint4*)&Blo[dd][ub + 8] = make_uint4(pk2(bl[8], bl[9]), pk2(bl[10], bl[11]),
                                                       pk2(bl[12], bl[13]), pk2(bl[14], bl[15]));
            }
            __syncthreads();
#pragma unroll
            for (int kk = 0; kk < 2; kk++) {
                int ko = kk * 32 + (lane >> 4) * 8;
                short8 a_h = *(const short8*)&Ahi[w * 16 + (lane & 15)][ko];
                short8 a_l = *(const short8*)&Alo[w * 16 + (lane & 15)][ko];
#pragma unroll
                for (int n = 0; n < 4; n++) {
                    short8 b_h = *(const short8*)&Bhi[n * 16 + (lane & 15)][ko];
                    short8 b_l = *(const short8*)&Blo[n * 16 + (lane & 15)][ko];
                    acc[n] = __builtin_amdgcn_mfma_f32_16x16x32_bf16(a_h, b_h, acc[n], 0, 0, 0);
                    acc[n] = __builtin_amdgcn_mfma_f32_16x16x32_bf16(a_h, b_l, acc[n], 0, 0, 0);
                    acc[n] = __builtin_amdgcn_mfma_f32_16x16x32_bf16(a_l, b_h, acc[n], 0, 0, 0);
                }
            }
            __syncthreads();
        }
        float* Mp = &M[(size_t)(j * SS_ + s) * 4096];
#pragma unroll
        for (int n = 0; n < 4; n++)
#pragma unroll
            for (int r = 0; r < 4; r++) {
                int c = w * 16 + (lane >> 4) * 4 + r;
                int dd = n * 16 + (lane & 15);
                Mp[c * 64 + dd] = acc[n][r];
            }
    }
}

// K10: out = (t_ij @ M) + (snr @ VC) via MFMA (hi/lo comp). grid(128 j, 5 s), block(256).
__global__ __launch_bounds__(256) void k_out(const float* __restrict__ M, const float* __restrict__ VC,
                                             const float* __restrict__ sn, const float* __restrict__ rsd,
                                             const float* __restrict__ tij, float* __restrict__ outb) {
    int j = blockIdx.x, s = blockIdx.y, t = threadIdx.x;
    int lane = t & 63, wv = t >> 6, l15 = lane & 15, quad = lane >> 4;
    __shared__ unsigned short Ahi[128][40], Alo[128][40];
    __shared__ unsigned short Bhi[64][40], Blo[64][40];
    f32x4 acc[2][4];
#pragma unroll
    for (int mt = 0; mt < 2; mt++)
#pragma unroll
        for (int nt = 0; nt < 4; nt++) acc[mt][nt] = (f32x4){0.f, 0.f, 0.f, 0.f};
    {
        int i = t >> 1, hg = (t & 1) * 4;
        unsigned short h4[4], l4[4];
#pragma unroll
        for (int e = 0; e < 4; e++) {
            int hh_ = hg + e;
            float v = sn[i * 1024 + hh_ * NN + j] * rsd[i * 40 + hh_ * SS_ + s];
            unsigned short hb = f2bf_u(v);
            h4[e] = hb;
            l4[e] = f2bf_u(v - bfu2f(hb));
        }
        *(uint2*)&Ahi[i][hg] = make_uint2(pk2(h4[0], h4[1]), pk2(h4[2], h4[3]));
        *(uint2*)&Alo[i][hg] = make_uint2(pk2(l4[0], l4[1]), pk2(l4[2], l4[3]));
#pragma unroll
        for (int r = 0; r < 2; r++) {
            int idx = t + r * 256;
            if (idx < 384) {
                int ii = idx / 3, g = idx % 3;
                *(uint4*)&Ahi[ii][8 + g * 8] = make_uint4(0, 0, 0, 0);
                *(uint4*)&Alo[ii][8 + g * 8] = make_uint4(0, 0, 0, 0);
            }
        }
        if (t < 64) {
            unsigned short h8[8], l8[8];
#pragma unroll
            for (int e = 0; e < 8; e++) {
                float v = VC[(size_t)(j * SS_ + s) * DI_ + e * 64 + t];
                unsigned short hb = f2bf_u(v);
                h8[e] = hb;
                l8[e] = f2bf_u(v - bfu2f(hb));
            }
            *(uint4*)&Bhi[t][0] = make_uint4(pk2(h8[0], h8[1]), pk2(h8[2], h8[3]),
                                             pk2(h8[4], h8[5]), pk2(h8[6], h8[7]));
            *(uint4*)&Blo[t][0] = make_uint4(pk2(l8[0], l8[1]), pk2(l8[2], l8[3]),
                                             pk2(l8[4], l8[5]), pk2(l8[6], l8[7]));
        } else {
            int idx = t - 64;
            int dd2 = idx / 3, g = idx % 3;
            *(uint4*)&Bhi[dd2][8 + g * 8] = make_uint4(0, 0, 0, 0);
            *(uint4*)&Blo[dd2][8 + g * 8] = make_uint4(0, 0, 0, 0);
        }
    }
    __syncthreads();
    {
        int ko = quad * 8;
        short8 a_h0 = *(const short8*)&Ahi[(wv * 2 + 0) * 16 + l15][ko];
        short8 a_l0 = *(const short8*)&Alo[(wv * 2 + 0) * 16 + l15][ko];
        short8 a_h1 = *(const short8*)&Ahi[(wv * 2 + 1) * 16 + l15][ko];
        short8 a_l1 = *(const short8*)&Alo[(wv * 2 + 1) * 16 + l15][ko];
#pragma unroll
        for (int nt = 0; nt < 4; nt++) {
            short8 b_h = *(const short8*)&Bhi[nt * 16 + l15][ko];
            short8 b_l = *(const short8*)&Blo[nt * 16 + l15][ko];
            acc[0][nt] = __builtin_amdgcn_mfma_f32_16x16x32_bf16(a_h0, b_h, acc[0][nt], 0, 0, 0);
            acc[0][nt] = __builtin_amdgcn_mfma_f32_16x16x32_bf16(a_h0, b_l, acc[0][nt], 0, 0, 0);
            acc[0][nt] = __builtin_amdgcn_mfma_f32_16x16x32_bf16(a_l0, b_h, acc[0][nt], 0, 0, 0);
            acc[1][nt] = __builtin_amdgcn_mfma_f32_16x16x32_bf16(a_h1, b_h, acc[1][nt], 0, 0, 0);
            acc[1][nt] = __builtin_amdgcn_mfma_f32_16x16x32_bf16(a_h1, b_l, acc[1][nt], 0, 0, 0);
            acc[1][nt] = __builtin_amdgcn_mfma_f32_16x16x32_bf16(a_l1, b_h, acc[1][nt], 0, 0, 0);
        }
    }
    for (int kc = 0; kc < 2; kc++) {
        __syncthreads();
        {
            int i = t >> 1, chalf = (t & 1) * 16;
            unsigned short h16[16], l16[16];
            const float* tp = &tij[(size_t)(i * NN + j) * DD_ + kc * 32 + chalf];
#pragma unroll
            for (int e = 0; e < 16; e += 4) {
                float4 v = *(const float4*)(tp + e);
                float vv[4] = {v.x, v.y, v.z, v.w};
#pragma unroll
                for (int z = 0; z < 4; z++) {
                    unsigned short hb = f2bf_u(vv[z]);
                    h16[e + z] = hb;
                    l16[e + z] = f2bf_u(vv[z] - bfu2f(hb));
                }
            }
            *(uint4*)&Ahi[i][chalf] = make_uint4(pk2(h16[0], h16[1]), pk2(h16[2], h16[3]),
                                                 pk2(h16[4], h16[5]), pk2(h16[6], h16[7]));
            *(uint4*)&Ahi[i][chalf + 8] = make_uint4(pk2(h16[8], h16[9]), pk2(h16[10], h16[11]),
                                                     pk2(h16[12], h16[13]), pk2(h16[14], h16[15]));
            *(uint4*)&Alo[i][chalf] = make_uint4(pk2(l16[0], l16[1]), pk2(l16[2], l16[3]),
                                                 pk2(l16[4], l16[5]), pk2(l16[6], l16[7]));
            *(uint4*)&Alo[i][chalf + 8] = make_uint4(pk2(l16[8], l16[9]), pk2(l16[10], l16[11]),
                                                     pk2(l16[12], l16[13]), pk2(l16[14], l16[15]));
        }
        {
            int dd2 = t & 63, cg = (t >> 6) * 8;
            unsigned short h8[8], l8[8];
#pragma unroll
            for (int e = 0; e < 8; e++) {
                float v = M[(size_t)(j * SS_ + s) * 4096 + (size_t)(kc * 32 + cg + e) * 64 + dd2];
                unsigned short hb = f2bf_u(v);
                h8[e] = hb;
                l8[e] = f2bf_u(v - bfu2f(hb));
            }
            *(uint4*)&Bhi[dd2][cg] = make_uint4(pk2(h8[0], h8[1]), pk2(h8[2], h8[3]),
                                                pk2(h8[4], h8[5]), pk2(h8[6], h8[7]));
            *(uint4*)&Blo[dd2][cg] = make_uint4(pk2(l8[0], l8[1]), pk2(l8[2], l8[3]),
                                                pk2(l8[4], l8[5]), pk2(l8[6], l8[7]));
        }
        __syncthreads();
        int ko = quad * 8;
        short8 a_h0 = *(const short8*)&Ahi[(wv * 2 + 0) * 16 + l15][ko];
        short8 a_l0 = *(const short8*)&Alo[(wv * 2 + 0) * 16 + l15][ko];
        short8 a_h1 = *(const short8*)&Ahi[(wv * 2 + 1) * 16 + l15][ko];
        short8 a_l1 = *(const short8*)&Alo[(wv * 2 + 1) * 16 + l15][ko];
#pragma unroll
        for (int nt = 0; nt < 4; nt++) {
            short8 b_h = *(const short8*)&Bhi[nt * 16 + l15][ko];
            short8 b_l = *(const short8*)&Blo[nt * 16 + l15][ko];
            acc[0][nt] = __builtin_amdgcn_mfma_f32_16x16x32_bf16(a_h0, b_h, acc[0][nt], 0, 0, 0);
            acc[0][nt] = __builtin_amdgcn_mfma_f32_16x16x32_bf16(a_h0, b_l, acc[0][nt], 0, 0, 0);
            acc[0][nt] = __builtin_amdgcn_mfma_f32_16x16x32_bf16(a_l0, b_h, acc[0][nt], 0, 0, 0);
            acc[1][nt] = __builtin_amdgcn_mfma_f32_16x16x32_bf16(a_h1, b_h, acc[1][nt], 0, 0, 0);
            acc[1][nt] = __builtin_amdgcn_mfma_f32_16x16x32_bf16(a_h1, b_l, acc[1][nt], 0, 0, 0);
            acc[1][nt] = __builtin_amdgcn_mfma_f32_16x16x32_bf16(a_l1, b_h, acc[1][nt], 0, 0, 0);
        }
    }
#pragma unroll
    for (int mt = 0; mt < 2; mt++)
#pragma unroll
        for (int nt = 0; nt < 4; nt++)
#pragma unroll
            for (int r = 0; r < 4; r++) {
                int i = (wv * 2 + mt) * 16 + quad * 4 + r;
                int dd = nt * 16 + l15;
                outb[((size_t)(i * NN + j) * SS_ + s) * 64 + dd] = acc[mt][nt][r];
            }
}

// K_redF: fused j-reduction + moment contraction + combine + store.
// grid(128 i), block(640): two j-halves in registers, combined via LDS.
__global__ __launch_bounds__(640) void k_redF(const float* __restrict__ outb,
                                              const float* __restrict__ r1, const float* __restrict__ r2,
                                              const float* __restrict__ x1, const float* __restrict__ x2,
                                              const float* __restrict__ h, float* __restrict__ dst) {
    int i = blockIdx.x, t = threadIdx.x;
    int half = (t >= 320) ? 1 : 0;
    int tt = t - half * 320;
    int s = tt >> 6, dd = tt & 63;
    float am[5] = {0.f, 0.f, 0.f, 0.f, 0.f};
    int jbeg = half * 64;
    for (int jj = 0; jj < 64; jj++) {
        int j = jbeg + jj;
        float ov = outb[((size_t)(i * NN + j) * SS_ + s) * 64 + dd];
        if (s == 0) {
            am[0] += ov;
        } else if (s == 1) {
#pragma unroll
            for (int m = 0; m < 3; m++) am[m] += r1[(i * NN + j) * 3 + m] * ov;
        } else if (s == 2) {
#pragma unroll
            for (int m = 0; m < 5; m++) am[m] += r2[(i * NN + j) * 5 + m] * ov;
        } else if (s == 3) {
#pragma unroll
            for (int m = 0; m < 3; m++) am[m] += x1[(j * DD_ + dd) * 3 + m] * ov;
        } else {
#pragma unroll
            for (int m = 0; m < 5; m++) am[m] += x2[(j * DD_ + dd) * 5 + m] * ov;
        }
    }
    __shared__ float lds[2][5][64][5];
#pragma unroll
    for (int m = 0; m < 5; m++) lds[half][s][dd][m] = am[m];
    __syncthreads();
    if (half == 0) {
        if (s == 0) {
            float v = lds[0][0][dd][0] + lds[1][0][dd][0];
            dst[i * DD_ + dd] = h[i * DD_ + dd] + v;
        } else if (s == 1) {
#pragma unroll
            for (int m = 0; m < 3; m++) {
                float v = lds[0][1][dd][m] + lds[1][1][dd][m] + lds[0][3][dd][m] + lds[1][3][dd][m];
                dst[8192 + (i * DD_ + dd) * 3 + m] = v;
            }
        } else if (s == 2) {
#pragma unroll
            for (int m = 0; m < 5; m++) {
                float v = lds[0][2][dd][m] + lds[1][2][dd][m] + lds[0][4][dd][m] + lds[1][4][dd][m];
                dst[8192 + 24576 + (i * DD_ + dd) * 5 + m] = v;
            }
        }
    }
}

extern "C" void kernel_launch(void* const* d_in, const int* in_sizes, int n_in,
                              void* d_out, int out_size, void* d_ws, size_t ws_size,
                              hipStream_t stream) {
    const float* h_in = (const float*)d_in[0];
    const float* tij = (const float*)d_in[1];
    const float* r1 = (const float*)d_in[2];
    const float* r2 = (const float*)d_in[3];
    const float* x1 = (const float*)d_in[4];
    const float* x2 = (const float*)d_in[5];
    const float* ghi = (const float*)d_in[6];
    const float* ghj = (const float*)d_in[7];
    const float* Wq = (const float*)d_in[8];
    const float* Wk = (const float*)d_in[9];
    const float* Wv1 = (const float*)d_in[10];
    const float* bv1 = (const float*)d_in[11];
    const float* Wv2 = (const float*)d_in[12];
    const float* bv2 = (const float*)d_in[13];
    const float* Wp1 = (const float*)d_in[14];
    const float* bp1 = (const float*)d_in[15];
    const float* Wp2 = (const float*)d_in[16];
    const float* bp2 = (const float*)d_in[17];
    const float* Wev = (const float*)d_in[18];
    const float* Wc = (const float*)d_in[19];
    float* dst = (float*)d_out;

    float* w = (float*)d_ws;
    size_t off = 16;
    auto alloc = [&](size_t n) { float* p = w + off; off += n; return p; };
    float* q    = alloc(65536);
    float* k    = alloc(65536);
    float* a1   = alloc(131072);
    float* p1   = alloc(131072);
    float* VC   = alloc(327680);
    float* sn   = alloc(131072);
    float* rsd  = alloc(5120);
    float* M    = alloc(2621440);
    float* outb = alloc(5242880);
    float* part = alloc(2621440);   // 4 x 655360 split-K partials

    k_front<<<dim3(128, 4), dim3(256), 0, stream>>>(h_in, ghi, ghj, Wq, Wk, Wv1, bv1, Wp1, bp1,
                                                    q, k, a1, p1);
    k_mid<<<dim3(960), dim3(256), 0, stream>>>(a1, p1, Wv2, Wp2, part, tij, Wev, q, rsd, k, sn);
    k_mid2<<<dim3(1280), dim3(256), 0, stream>>>(part, bv2, bp2, Wc, Wev, VC, M);
    k_out<<<dim3(128, 5), dim3(256), 0, stream>>>(M, VC, sn, rsd, tij, outb);
    k_redF<<<dim3(128), dim3(640), 0, stream>>>(outb, r1, r2, x1, x2, h_in, dst);
}

// Round 2
// 213.616 us; speedup vs baseline: 1.1146x; 1.1146x over previous
//
#include <hip/hip_runtime.h>
#include <hip/hip_bf16.h>

typedef __hip_bfloat16 bf16;
typedef __attribute__((ext_vector_type(8))) short short8;
typedef __attribute__((ext_vector_type(4))) float f32x4;

#define NN 128
#define DD_ 64
#define HH_ 8
#define DH_ 64
#define DI_ 512
#define SS_ 5
#define MLPD 1024
#define SDI 2560
#define KS2 4
#define KCM 64

__device__ __forceinline__ float wave_sum64(float v) {
#pragma unroll
    for (int off = 32; off > 0; off >>= 1) v += __shfl_xor(v, off, 64);
    return v;
}

__device__ __forceinline__ unsigned short f2bf_u(float f) {
    unsigned u = __float_as_uint(f);
    u += 0x7FFF + ((u >> 16) & 1);
    return (unsigned short)(u >> 16);
}
__device__ __forceinline__ float bfu2f(unsigned short s) {
    return __uint_as_float(((unsigned)s) << 16);
}
__device__ __forceinline__ unsigned pk2(unsigned short a, unsigned short b) {
    return (unsigned)a | ((unsigned)b << 16);
}

// K1: fused LN + q/k + mlp1 (blocks 0..511) + T-sum of tij (blocks 512..639).
__global__ __launch_bounds__(256) void k_front(
    const float* __restrict__ h, const float* __restrict__ ghi, const float* __restrict__ ghj,
    const float* __restrict__ Wq, const float* __restrict__ Wk,
    const float* __restrict__ Wv1, const float* __restrict__ bv1,
    const float* __restrict__ Wp1, const float* __restrict__ bp1,
    const float* __restrict__ tij,
    float* __restrict__ q, float* __restrict__ k,
    float* __restrict__ a1, float* __restrict__ p1, float* __restrict__ T) {
    int b = blockIdx.x, t = threadIdx.x;
    if (b >= 512) {
        // ---- T[i][c] = sum_j tij[i][j][c]
        int i = b - 512;
        __shared__ float red[4][64];
        int c = t & 63, jg = t >> 6;
        float s = 0.f;
        for (int j = jg; j < NN; j += 4) s += tij[(size_t)(i * NN + j) * DD_ + c];
        red[jg][c] = s;
        __syncthreads();
        if (t < 64) T[i * 64 + t] = red[0][t] + red[1][t] + red[2][t] + red[3][t];
        return;
    }
    int i = b & 127, ch = b >> 7;
    int d = t & 63;
    __shared__ float hib[DD_], hjb[DD_];
    float x = h[i * DD_ + d];
    float s = wave_sum64(x);
    float s2 = wave_sum64(x * x);
    float m = s * (1.0f / DD_);
    float v = s2 * (1.0f / DD_) - m * m;
    float r = rsqrtf(v + 1e-5f);
    float xc = (x - m) * r;
    if (t < 64) { hib[d] = xc * ghi[d]; hjb[d] = xc * ghj[d]; }
    __syncthreads();
    {
        int c = ch * 128 + (t & 127);
        const float* W = (t < 128) ? Wq : Wk;
        const float* hb = (t < 128) ? hib : hjb;
        float a = 0.f;
#pragma unroll 8
        for (int dd = 0; dd < DD_; dd++) a += hb[dd] * W[dd * DI_ + c];
        float* dstqk = (t < 128) ? q : k;
        dstqk[i * DI_ + c] = a;
    }
    {
        int c = ch * 256 + t;
        float av = 0.f, ap = 0.f;
#pragma unroll 4
        for (int dd = 0; dd < DD_; dd++) {
            float hv = hjb[dd];
            av += hv * Wv1[dd * MLPD + c];
            ap += hv * Wp1[dd * MLPD + c];
        }
        float xv = av + bv1[c], xp = ap + bp1[c];
        a1[i * MLPD + c] = xv / (1.0f + expf(-xv));
        p1[i * MLPD + c] = xp / (1.0f + expf(-xp));
    }
}

// K_mid: fused mlp2 (blocks 0..319) + den (320..959, 128 i x 5 chunks) +
// simnum (960..1471). All depend only on k_front; one launch, concurrent.
__global__ __launch_bounds__(256) void k_mid(
    const float* __restrict__ a1, const float* __restrict__ p1,
    const float* __restrict__ Wv2, const float* __restrict__ Wp2,
    float* __restrict__ part,
    const float* __restrict__ T, const float* __restrict__ Wev,
    const float* __restrict__ q, float* __restrict__ rsd,
    const float* __restrict__ k, float* __restrict__ sn) {
    __shared__ __align__(16) unsigned char smem[30720];
    int b = blockIdx.x, t = threadIdx.x;
    if (b < 320) {
        // ---- mlp2: split-K MFMA GEMM (hi/lo bf16 compensation)
        unsigned short (*Ahi)[40] = (unsigned short (*)[40])(smem);
        unsigned short (*Alo)[40] = (unsigned short (*)[40])(smem + 10240);
        unsigned short (*Bhi)[40] = (unsigned short (*)[40])(smem + 20480);
        unsigned short (*Blo)[40] = (unsigned short (*)[40])(smem + 25600);
        int ct = b % 80, ks = b / 80;
        int c0 = ct * 64;
        bool isp = c0 >= 2560;
        int c0l = c0 - (isp ? 2560 : 0);
        const float* __restrict__ src = isp ? p1 : a1;
        const float* __restrict__ W = isp ? Wp2 : Wv2;
        int kbase = ks * 256;
        int lane = t & 63, wv = t >> 6;
        int l15 = lane & 15, quad = lane >> 4;
        f32x4 acc[2][4];
#pragma unroll
        for (int mt = 0; mt < 2; mt++)
#pragma unroll
            for (int nt = 0; nt < 4; nt++) acc[mt][nt] = (f32x4){0.f, 0.f, 0.f, 0.f};
        int aj = t >> 1, ak = (t & 1) * 16;
        int bc = t & 63, bk = (t >> 6) * 8;
        for (int kc = 0; kc < 8; kc++) {
            int k0 = kbase + kc * 32;
            __syncthreads();
            {
                unsigned short h16[16], l16[16];
                const float* ap = &src[(size_t)aj * MLPD + k0 + ak];
#pragma unroll
                for (int e = 0; e < 16; e += 4) {
                    float4 v = *(const float4*)(ap + e);
                    float vv[4] = {v.x, v.y, v.z, v.w};
#pragma unroll
                    for (int z = 0; z < 4; z++) {
                        unsigned short hb = f2bf_u(vv[z]);
                        h16[e + z] = hb;
                        l16[e + z] = f2bf_u(vv[z] - bfu2f(hb));
                    }
                }
                *(uint4*)&Ahi[aj][ak] = make_uint4(pk2(h16[0], h16[1]), pk2(h16[2], h16[3]),
                                                   pk2(h16[4], h16[5]), pk2(h16[6], h16[7]));
                *(uint4*)&Ahi[aj][ak + 8] = make_uint4(pk2(h16[8], h16[9]), pk2(h16[10], h16[11]),
                                                       pk2(h16[12], h16[13]), pk2(h16[14], h16[15]));
                *(uint4*)&Alo[aj][ak] = make_uint4(pk2(l16[0], l16[1]), pk2(l16[2], l16[3]),
                                                   pk2(l16[4], l16[5]), pk2(l16[6], l16[7]));
                *(uint4*)&Alo[aj][ak + 8] = make_uint4(pk2(l16[8], l16[9]), pk2(l16[10], l16[11]),
                                                       pk2(l16[12], l16[13]), pk2(l16[14], l16[15]));
            }
            {
                unsigned short h8[8], l8[8];
#pragma unroll
                for (int e = 0; e < 8; e++) {
                    float v = W[(size_t)(k0 + bk + e) * SDI + c0l + bc];
                    unsigned short hb = f2bf_u(v);
                    h8[e] = hb;
                    l8[e] = f2bf_u(v - bfu2f(hb));
                }
                *(uint4*)&Bhi[bc][bk] = make_uint4(pk2(h8[0], h8[1]), pk2(h8[2], h8[3]),
                                                   pk2(h8[4], h8[5]), pk2(h8[6], h8[7]));
                *(uint4*)&Blo[bc][bk] = make_uint4(pk2(l8[0], l8[1]), pk2(l8[2], l8[3]),
                                                   pk2(l8[4], l8[5]), pk2(l8[6], l8[7]));
            }
            __syncthreads();
            int ko = quad * 8;
            short8 a_h0 = *(const short8*)&Ahi[(wv * 2 + 0) * 16 + l15][ko];
            short8 a_l0 = *(const short8*)&Alo[(wv * 2 + 0) * 16 + l15][ko];
            short8 a_h1 = *(const short8*)&Ahi[(wv * 2 + 1) * 16 + l15][ko];
            short8 a_l1 = *(const short8*)&Alo[(wv * 2 + 1) * 16 + l15][ko];
#pragma unroll
            for (int nt = 0; nt < 4; nt++) {
                short8 b_h = *(const short8*)&Bhi[nt * 16 + l15][ko];
                short8 b_l = *(const short8*)&Blo[nt * 16 + l15][ko];
                acc[0][nt] = __builtin_amdgcn_mfma_f32_16x16x32_bf16(a_h0, b_h, acc[0][nt], 0, 0, 0);
                acc[0][nt] = __builtin_amdgcn_mfma_f32_16x16x32_bf16(a_h0, b_l, acc[0][nt], 0, 0, 0);
                acc[0][nt] = __builtin_amdgcn_mfma_f32_16x16x32_bf16(a_l0, b_h, acc[0][nt], 0, 0, 0);
                acc[1][nt] = __builtin_amdgcn_mfma_f32_16x16x32_bf16(a_h1, b_h, acc[1][nt], 0, 0, 0);
                acc[1][nt] = __builtin_amdgcn_mfma_f32_16x16x32_bf16(a_h1, b_l, acc[1][nt], 0, 0, 0);
                acc[1][nt] = __builtin_amdgcn_mfma_f32_16x16x32_bf16(a_l1, b_h, acc[1][nt], 0, 0, 0);
            }
        }
#pragma unroll
        for (int mt = 0; mt < 2; mt++)
#pragma unroll
            for (int nt = 0; nt < 4; nt++)
#pragma unroll
                for (int r = 0; r < 4; r++) {
                    int j = (wv * 2 + mt) * 16 + quad * 4 + r;
                    int cc = c0 + nt * 16 + l15;
                    part[(size_t)ks * 655360 + (size_t)j * 5120 + cc] = acc[mt][nt][r];
                }
    } else if (b < 960) {
        // ---- den: EV dot + rsd. 128 i x 5 u-chunks, 512 cols/block.
        float* Tl = (float*)smem;          // 64
        float* ql = (float*)(smem + 256);  // 512
        int idx = b - 320;
        int i = idx & 127, chunk = idx >> 7;
        if (t < 64) Tl[t] = T[i * 64 + t];
        ql[t] = q[i * DI_ + t];
        ql[t + 256] = q[i * DI_ + t + 256];
        __syncthreads();
#pragma unroll
        for (int kx = 0; kx < 2; kx++) {
            int u = chunk * 512 + kx * 256 + t;
            float ev = 0.f;
#pragma unroll 8
            for (int cc = 0; cc < DD_; cc++) ev += Tl[cc] * Wev[(size_t)cc * SDI + u];
            float den = wave_sum64(ev * ql[u & 511]);
            if ((t & 63) == 0) {
                int g = u >> 6;
                int ss = g >> 3, hh = g & 7;
                rsd[i * 40 + hh * SS_ + ss] = 1.0f / den;
            }
        }
    } else {
        // ---- simnum: 2 heads per block (256 threads)
        float* qb = (float*)smem;  // 128
        int idx = b - 960;
        int i = idx & 127, yh = idx >> 7;
        if (t < 128) qb[t] = q[i * DI_ + yh * 128 + t];
        __syncthreads();
        int hh = yh * 2 + (t >> 7), j = t & 127;
        float a = 0.f;
        const float* kr = &k[(size_t)j * DI_ + hh * DH_];
        const float* qr = &qb[(t >> 7) * 64];
#pragma unroll 8
        for (int d = 0; d < DH_; d++) a += qr[d] * kr[d];
        sn[i * 1024 + hh * NN + j] = a;
    }
}

// K_mid2: fused VC (blocks 0..639) + M (640..1279). M-branch reduces the
// pav partials from `part` inline.
__global__ __launch_bounds__(256) void k_mid2(
    const float* __restrict__ part, const float* __restrict__ bv2,
    const float* __restrict__ bp2, const float* __restrict__ Wc,
    const float* __restrict__ Wev, float* __restrict__ VC, float* __restrict__ M) {
    __shared__ __align__(16) unsigned char smem[38912];
    int b = blockIdx.x, t = threadIdx.x;
    if (b < 640) {
        float* vlds = (float*)smem;  // 512
        int j = b & 127, s = b >> 7;
#pragma unroll
        for (int r = 0; r < 2; r++) {
            int tt = r * 256 + t;
            int e = s * 512 + tt;
            float sum = 0.f;
#pragma unroll
            for (int p = 0; p < KS2; p++) sum += part[(size_t)p * 655360 + (size_t)j * 5120 + e];
            vlds[tt] = sum + bv2[e];
        }
        __syncthreads();
#pragma unroll
        for (int r = 0; r < 2; r++) {
            int tt = r * 256 + t;
            int dd = tt & 63;
            int hbase = tt - dd;
            float acc = 0.f;
#pragma unroll 8
            for (int d2 = 0; d2 < DH_; d2++)
                acc += vlds[hbase + d2] * Wc[(size_t)(hbase + d2) * DD_ + dd];
            VC[(size_t)(j * SS_ + s) * DI_ + tt] = acc;
        }
    } else {
        int idx = b - 640;
        int j = idx & 127, s = idx >> 7;
        int lane = t & 63, w = t >> 6;
        float* P = (float*)smem;  // 512 floats
        unsigned short (*Ahi)[72] = (unsigned short (*)[72])(smem + 2048);
        unsigned short (*Alo)[72] = (unsigned short (*)[72])(smem + 11264);
        unsigned short (*Bhi)[72] = (unsigned short (*)[72])(smem + 20480);
        unsigned short (*Blo)[72] = (unsigned short (*)[72])(smem + 29696);
        {
            int e = 2560 + s * 512 + t;
            float s0 = 0.f, s1 = 0.f;
#pragma unroll
            for (int p = 0; p < KS2; p++) {
                s0 += part[(size_t)p * 655360 + (size_t)j * 5120 + e];
                s1 += part[(size_t)p * 655360 + (size_t)j * 5120 + e + 256];
            }
            P[t] = s0 + bp2[s * 512 + t];
            P[t + 256] = s1 + bp2[s * 512 + t + 256];
        }
        f32x4 acc[4];
#pragma unroll
        for (int n = 0; n < 4; n++) acc[n] = (f32x4){0.f, 0.f, 0.f, 0.f};
        __syncthreads();
        for (int u0 = 0; u0 < DI_; u0 += KCM) {
            {
                int c = t >> 2, ug = (t & 3) * 16;
                const float* wevp = &Wev[(size_t)c * SDI + s * DI_ + u0 + ug];
                unsigned short ah[16], al[16];
#pragma unroll
                for (int e = 0; e < 16; e += 4) {
                    float4 wv = *(const float4*)(wevp + e);
                    float4 pv = *(const float4*)&P[u0 + ug + e];
                    float av[4] = {wv.x * pv.x, wv.y * pv.y, wv.z * pv.z, wv.w * pv.w};
#pragma unroll
                    for (int z = 0; z < 4; z++) {
                        unsigned short hh2 = f2bf_u(av[z]);
                        ah[e + z] = hh2;
                        al[e + z] = f2bf_u(av[z] - bfu2f(hh2));
                    }
                }
                *(uint4*)&Ahi[c][ug] = make_uint4(pk2(ah[0], ah[1]), pk2(ah[2], ah[3]),
                                                  pk2(ah[4], ah[5]), pk2(ah[6], ah[7]));
                *(uint4*)&Ahi[c][ug + 8] = make_uint4(pk2(ah[8], ah[9]), pk2(ah[10], ah[11]),
                                                      pk2(ah[12], ah[13]), pk2(ah[14], ah[15]));
                *(uint4*)&Alo[c][ug] = make_uint4(pk2(al[0], al[1]), pk2(al[2], al[3]),
                                                  pk2(al[4], al[5]), pk2(al[6], al[7]));
                *(uint4*)&Alo[c][ug + 8] = make_uint4(pk2(al[8], al[9]), pk2(al[10], al[11]),
                                                      pk2(al[12], al[13]), pk2(al[14], al[15]));
            }
            {
                int dd = t & 63, ub = (t >> 6) * 16;
                unsigned short bh[16], bl[16];
#pragma unroll
                for (int e = 0; e < 16; e++) {
                    float v = Wc[(size_t)(u0 + ub + e) * DD_ + dd];
                    unsigned short hh2 = f2bf_u(v);
                    bh[e] = hh2;
                    bl[e] = f2bf_u(v - bfu2f(hh2));
                }
                *(uint4*)&Bhi[dd][ub] = make_uint4(pk2(bh[0], bh[1]), pk2(bh[2], bh[3]),
                                                   pk2(bh[4], bh[5]), pk2(bh[6], bh[7]));
                *(uint4*)&Bhi[dd][ub + 8] = make_uint4(pk2(bh[8], bh[9]), pk2(bh[10], bh[11]),
                                                       pk2(bh[12], bh[13]), pk2(bh[14], bh[15]));
                *(uint4*)&Blo[dd][ub] = make_uint4(pk2(bl[0], bl[1]), pk2(bl[2], bl[3]),
                                                   pk2(bl[4], bl[5]), pk2(bl[6], bl[7]));
                *(uint4*)&Blo[dd][ub + 8] = make_uint4(pk2(bl[8], bl[9]), pk2(bl[10], bl[11]),
                                                       pk2(bl[12], bl[13]), pk2(bl[14], bl[15]));
            }
            __syncthreads();
#pragma unroll
            for (int kk = 0; kk < 2; kk++) {
                int ko = kk * 32 + (lane >> 4) * 8;
                short8 a_h = *(const short8*)&Ahi[w * 16 + (lane & 15)][ko];
                short8 a_l = *(const short8*)&Alo[w * 16 + (lane & 15)][ko];
#pragma unroll
                for (int n = 0; n < 4; n++) {
                    short8 b_h = *(const short8*)&Bhi[n * 16 + (lane & 15)][ko];
                    short8 b_l = *(const short8*)&Blo[n * 16 + (lane & 15)][ko];
                    acc[n] = __builtin_amdgcn_mfma_f32_16x16x32_bf16(a_h, b_h, acc[n], 0, 0, 0);
                    acc[n] = __builtin_amdgcn_mfma_f32_16x16x32_bf16(a_h, b_l, acc[n], 0, 0, 0);
                    acc[n] = __builtin_amdgcn_mfma_f32_16x16x32_bf16(a_l, b_h, acc[n], 0, 0, 0);
                }
            }
            __syncthreads();
        }
        float* Mp = &M[(size_t)(j * SS_ + s) * 4096];
#pragma unroll
        for (int n = 0; n < 4; n++)
#pragma unroll
            for (int r = 0; r < 4; r++) {
                int c = w * 16 + (lane >> 4) * 4 + r;
                int dd = n * 16 + (lane & 15);
                Mp[c * 64 + dd] = acc[n][r];
            }
    }
}

// K10: out = (t_ij @ M) + (snr @ VC) via MFMA (hi/lo comp). grid(128 j, 5 s), block(256).
__global__ __launch_bounds__(256) void k_out(const float* __restrict__ M, const float* __restrict__ VC,
                                             const float* __restrict__ sn, const float* __restrict__ rsd,
                                             const float* __restrict__ tij, float* __restrict__ outb) {
    int j = blockIdx.x, s = blockIdx.y, t = threadIdx.x;
    int lane = t & 63, wv = t >> 6, l15 = lane & 15, quad = lane >> 4;
    __shared__ unsigned short Ahi[128][40], Alo[128][40];
    __shared__ unsigned short Bhi[64][40], Blo[64][40];
    f32x4 acc[2][4];
#pragma unroll
    for (int mt = 0; mt < 2; mt++)
#pragma unroll
        for (int nt = 0; nt < 4; nt++) acc[mt][nt] = (f32x4){0.f, 0.f, 0.f, 0.f};
    {
        int i = t >> 1, hg = (t & 1) * 4;
        unsigned short h4[4], l4[4];
#pragma unroll
        for (int e = 0; e < 4; e++) {
            int hh_ = hg + e;
            float v = sn[i * 1024 + hh_ * NN + j] * rsd[i * 40 + hh_ * SS_ + s];
            unsigned short hb = f2bf_u(v);
            h4[e] = hb;
            l4[e] = f2bf_u(v - bfu2f(hb));
        }
        *(uint2*)&Ahi[i][hg] = make_uint2(pk2(h4[0], h4[1]), pk2(h4[2], h4[3]));
        *(uint2*)&Alo[i][hg] = make_uint2(pk2(l4[0], l4[1]), pk2(l4[2], l4[3]));
#pragma unroll
        for (int r = 0; r < 2; r++) {
            int idx = t + r * 256;
            if (idx < 384) {
                int ii = idx / 3, g = idx % 3;
                *(uint4*)&Ahi[ii][8 + g * 8] = make_uint4(0, 0, 0, 0);
                *(uint4*)&Alo[ii][8 + g * 8] = make_uint4(0, 0, 0, 0);
            }
        }
        if (t < 64) {
            unsigned short h8[8], l8[8];
#pragma unroll
            for (int e = 0; e < 8; e++) {
                float v = VC[(size_t)(j * SS_ + s) * DI_ + e * 64 + t];
                unsigned short hb = f2bf_u(v);
                h8[e] = hb;
                l8[e] = f2bf_u(v - bfu2f(hb));
            }
            *(uint4*)&Bhi[t][0] = make_uint4(pk2(h8[0], h8[1]), pk2(h8[2], h8[3]),
                                             pk2(h8[4], h8[5]), pk2(h8[6], h8[7]));
            *(uint4*)&Blo[t][0] = make_uint4(pk2(l8[0], l8[1]), pk2(l8[2], l8[3]),
                                             pk2(l8[4], l8[5]), pk2(l8[6], l8[7]));
        } else {
            int idx = t - 64;
            int dd2 = idx / 3, g = idx % 3;
            *(uint4*)&Bhi[dd2][8 + g * 8] = make_uint4(0, 0, 0, 0);
            *(uint4*)&Blo[dd2][8 + g * 8] = make_uint4(0, 0, 0, 0);
        }
    }
    __syncthreads();
    {
        int ko = quad * 8;
        short8 a_h0 = *(const short8*)&Ahi[(wv * 2 + 0) * 16 + l15][ko];
        short8 a_l0 = *(const short8*)&Alo[(wv * 2 + 0) * 16 + l15][ko];
        short8 a_h1 = *(const short8*)&Ahi[(wv * 2 + 1) * 16 + l15][ko];
        short8 a_l1 = *(const short8*)&Alo[(wv * 2 + 1) * 16 + l15][ko];
#pragma unroll
        for (int nt = 0; nt < 4; nt++) {
            short8 b_h = *(const short8*)&Bhi[nt * 16 + l15][ko];
            short8 b_l = *(const short8*)&Blo[nt * 16 + l15][ko];
            acc[0][nt] = __builtin_amdgcn_mfma_f32_16x16x32_bf16(a_h0, b_h, acc[0][nt], 0, 0, 0);
            acc[0][nt] = __builtin_amdgcn_mfma_f32_16x16x32_bf16(a_h0, b_l, acc[0][nt], 0, 0, 0);
            acc[0][nt] = __builtin_amdgcn_mfma_f32_16x16x32_bf16(a_l0, b_h, acc[0][nt], 0, 0, 0);
            acc[1][nt] = __builtin_amdgcn_mfma_f32_16x16x32_bf16(a_h1, b_h, acc[1][nt], 0, 0, 0);
            acc[1][nt] = __builtin_amdgcn_mfma_f32_16x16x32_bf16(a_h1, b_l, acc[1][nt], 0, 0, 0);
            acc[1][nt] = __builtin_amdgcn_mfma_f32_16x16x32_bf16(a_l1, b_h, acc[1][nt], 0, 0, 0);
        }
    }
    for (int kc = 0; kc < 2; kc++) {
        __syncthreads();
        {
            int i = t >> 1, chalf = (t & 1) * 16;
            unsigned short h16[16], l16[16];
            const float* tp = &tij[(size_t)(i * NN + j) * DD_ + kc * 32 + chalf];
#pragma unroll
            for (int e = 0; e < 16; e += 4) {
                float4 v = *(const float4*)(tp + e);
                float vv[4] = {v.x, v.y, v.z, v.w};
#pragma unroll
                for (int z = 0; z < 4; z++) {
                    unsigned short hb = f2bf_u(vv[z]);
                    h16[e + z] = hb;
                    l16[e + z] = f2bf_u(vv[z] - bfu2f(hb));
                }
            }
            *(uint4*)&Ahi[i][chalf] = make_uint4(pk2(h16[0], h16[1]), pk2(h16[2], h16[3]),
                                                 pk2(h16[4], h16[5]), pk2(h16[6], h16[7]));
            *(uint4*)&Ahi[i][chalf + 8] = make_uint4(pk2(h16[8], h16[9]), pk2(h16[10], h16[11]),
                                                     pk2(h16[12], h16[13]), pk2(h16[14], h16[15]));
            *(uint4*)&Alo[i][chalf] = make_uint4(pk2(l16[0], l16[1]), pk2(l16[2], l16[3]),
                                                 pk2(l16[4], l16[5]), pk2(l16[6], l16[7]));
            *(uint4*)&Alo[i][chalf + 8] = make_uint4(pk2(l16[8], l16[9]), pk2(l16[10], l16[11]),
                                                     pk2(l16[12], l16[13]), pk2(l16[14], l16[15]));
        }
        {
            int dd2 = t & 63, cg = (t >> 6) * 8;
            unsigned short h8[8], l8[8];
#pragma unroll
            for (int e = 0; e < 8; e++) {
                float v = M[(size_t)(j * SS_ + s) * 4096 + (size_t)(kc * 32 + cg + e) * 64 + dd2];
                unsigned short hb = f2bf_u(v);
                h8[e] = hb;
                l8[e] = f2bf_u(v - bfu2f(hb));
            }
            *(uint4*)&Bhi[dd2][cg] = make_uint4(pk2(h8[0], h8[1]), pk2(h8[2], h8[3]),
                                                pk2(h8[4], h8[5]), pk2(h8[6], h8[7]));
            *(uint4*)&Blo[dd2][cg] = make_uint4(pk2(l8[0], l8[1]), pk2(l8[2], l8[3]),
                                                pk2(l8[4], l8[5]), pk2(l8[6], l8[7]));
        }
        __syncthreads();
        int ko = quad * 8;
        short8 a_h0 = *(const short8*)&Ahi[(wv * 2 + 0) * 16 + l15][ko];
        short8 a_l0 = *(const short8*)&Alo[(wv * 2 + 0) * 16 + l15][ko];
        short8 a_h1 = *(const short8*)&Ahi[(wv * 2 + 1) * 16 + l15][ko];
        short8 a_l1 = *(const short8*)&Alo[(wv * 2 + 1) * 16 + l15][ko];
#pragma unroll
        for (int nt = 0; nt < 4; nt++) {
            short8 b_h = *(const short8*)&Bhi[nt * 16 + l15][ko];
            short8 b_l = *(const short8*)&Blo[nt * 16 + l15][ko];
            acc[0][nt] = __builtin_amdgcn_mfma_f32_16x16x32_bf16(a_h0, b_h, acc[0][nt], 0, 0, 0);
            acc[0][nt] = __builtin_amdgcn_mfma_f32_16x16x32_bf16(a_h0, b_l, acc[0][nt], 0, 0, 0);
            acc[0][nt] = __builtin_amdgcn_mfma_f32_16x16x32_bf16(a_l0, b_h, acc[0][nt], 0, 0, 0);
            acc[1][nt] = __builtin_amdgcn_mfma_f32_16x16x32_bf16(a_h1, b_h, acc[1][nt], 0, 0, 0);
            acc[1][nt] = __builtin_amdgcn_mfma_f32_16x16x32_bf16(a_h1, b_l, acc[1][nt], 0, 0, 0);
            acc[1][nt] = __builtin_amdgcn_mfma_f32_16x16x32_bf16(a_l1, b_h, acc[1][nt], 0, 0, 0);
        }
    }
#pragma unroll
    for (int mt = 0; mt < 2; mt++)
#pragma unroll
        for (int nt = 0; nt < 4; nt++)
#pragma unroll
            for (int r = 0; r < 4; r++) {
                int i = (wv * 2 + mt) * 16 + quad * 4 + r;
                int dd = nt * 16 + l15;
                outb[((size_t)(i * NN + j) * SS_ + s) * 64 + dd] = acc[mt][nt][r];
            }
}

// K_redF: fused j-reduction + moment contraction + combine + store.
// grid(128 i), block(640): two j-halves in registers, combined via LDS.
__global__ __launch_bounds__(640) void k_redF(const float* __restrict__ outb,
                                              const float* __restrict__ r1, const float* __restrict__ r2,
                                              const float* __restrict__ x1, const float* __restrict__ x2,
                                              const float* __restrict__ h, float* __restrict__ dst) {
    int i = blockIdx.x, t = threadIdx.x;
    int half = (t >= 320) ? 1 : 0;
    int tt = t - half * 320;
    int s = tt >> 6, dd = tt & 63;
    float am[5] = {0.f, 0.f, 0.f, 0.f, 0.f};
    int jbeg = half * 64;
    for (int jj = 0; jj < 64; jj++) {
        int j = jbeg + jj;
        float ov = outb[((size_t)(i * NN + j) * SS_ + s) * 64 + dd];
        if (s == 0) {
            am[0] += ov;
        } else if (s == 1) {
#pragma unroll
            for (int m = 0; m < 3; m++) am[m] += r1[(i * NN + j) * 3 + m] * ov;
        } else if (s == 2) {
#pragma unroll
            for (int m = 0; m < 5; m++) am[m] += r2[(i * NN + j) * 5 + m] * ov;
        } else if (s == 3) {
#pragma unroll
            for (int m = 0; m < 3; m++) am[m] += x1[(j * DD_ + dd) * 3 + m] * ov;
        } else {
#pragma unroll
            for (int m = 0; m < 5; m++) am[m] += x2[(j * DD_ + dd) * 5 + m] * ov;
        }
    }
    __shared__ float lds[2][5][64][5];
#pragma unroll
    for (int m = 0; m < 5; m++) lds[half][s][dd][m] = am[m];
    __syncthreads();
    if (half == 0) {
        if (s == 0) {
            float v = lds[0][0][dd][0] + lds[1][0][dd][0];
            dst[i * DD_ + dd] = h[i * DD_ + dd] + v;
        } else if (s == 1) {
#pragma unroll
            for (int m = 0; m < 3; m++) {
                float v = lds[0][1][dd][m] + lds[1][1][dd][m] + lds[0][3][dd][m] + lds[1][3][dd][m];
                dst[8192 + (i * DD_ + dd) * 3 + m] = v;
            }
        } else if (s == 2) {
#pragma unroll
            for (int m = 0; m < 5; m++) {
                float v = lds[0][2][dd][m] + lds[1][2][dd][m] + lds[0][4][dd][m] + lds[1][4][dd][m];
                dst[8192 + 24576 + (i * DD_ + dd) * 5 + m] = v;
            }
        }
    }
}

extern "C" void kernel_launch(void* const* d_in, const int* in_sizes, int n_in,
                              void* d_out, int out_size, void* d_ws, size_t ws_size,
                              hipStream_t stream) {
    const float* h_in = (const float*)d_in[0];
    const float* tij = (const float*)d_in[1];
    const float* r1 = (const float*)d_in[2];
    const float* r2 = (const float*)d_in[3];
    const float* x1 = (const float*)d_in[4];
    const float* x2 = (const float*)d_in[5];
    const float* ghi = (const float*)d_in[6];
    const float* ghj = (const float*)d_in[7];
    const float* Wq = (const float*)d_in[8];
    const float* Wk = (const float*)d_in[9];
    const float* Wv1 = (const float*)d_in[10];
    const float* bv1 = (const float*)d_in[11];
    const float* Wv2 = (const float*)d_in[12];
    const float* bv2 = (const float*)d_in[13];
    const float* Wp1 = (const float*)d_in[14];
    const float* bp1 = (const float*)d_in[15];
    const float* Wp2 = (const float*)d_in[16];
    const float* bp2 = (const float*)d_in[17];
    const float* Wev = (const float*)d_in[18];
    const float* Wc = (const float*)d_in[19];
    float* dst = (float*)d_out;

    float* w = (float*)d_ws;
    size_t off = 16;
    auto alloc = [&](size_t n) { float* p = w + off; off += n; return p; };
    float* q    = alloc(65536);
    float* k    = alloc(65536);
    float* a1   = alloc(131072);
    float* p1   = alloc(131072);
    float* VC   = alloc(327680);
    float* sn   = alloc(131072);
    float* rsd  = alloc(5120);
    float* M    = alloc(2621440);
    float* outb = alloc(5242880);
    float* part = alloc(2621440);   // 4 x 655360 split-K partials
    float* T    = alloc(8192);      // 128 x 64 j-summed t_ij

    k_front<<<dim3(640), dim3(256), 0, stream>>>(h_in, ghi, ghj, Wq, Wk, Wv1, bv1, Wp1, bp1,
                                                 tij, q, k, a1, p1, T);
    k_mid<<<dim3(1472), dim3(256), 0, stream>>>(a1, p1, Wv2, Wp2, part, T, Wev, q, rsd, k, sn);
    k_mid2<<<dim3(1280), dim3(256), 0, stream>>>(part, bv2, bp2, Wc, Wev, VC, M);
    k_out<<<dim3(128, 5), dim3(256), 0, stream>>>(M, VC, sn, rsd, tij, outb);
    k_redF<<<dim3(128), dim3(640), 0, stream>>>(outb, r1, r2, x1, x2, h_in, dst);
}

// Round 3
// 201.767 us; speedup vs baseline: 1.1800x; 1.0587x over previous
//
#include <hip/hip_runtime.h>
#include <hip/hip_bf16.h>

typedef __hip_bfloat16 bf16;
typedef __attribute__((ext_vector_type(8))) short short8;
typedef __attribute__((ext_vector_type(4))) float f32x4;

#define NN 128
#define DD_ 64
#define HH_ 8
#define DH_ 64
#define DI_ 512
#define SS_ 5
#define MLPD 1024
#define SDI 2560
#define KS2 4
#define KCM 64

__device__ __forceinline__ float wave_sum64(float v) {
#pragma unroll
    for (int off = 32; off > 0; off >>= 1) v += __shfl_xor(v, off, 64);
    return v;
}

__device__ __forceinline__ unsigned short f2bf_u(float f) {
    unsigned u = __float_as_uint(f);
    u += 0x7FFF + ((u >> 16) & 1);
    return (unsigned short)(u >> 16);
}
__device__ __forceinline__ float bfu2f(unsigned short s) {
    return __uint_as_float(((unsigned)s) << 16);
}
__device__ __forceinline__ unsigned pk2(unsigned short a, unsigned short b) {
    return (unsigned)a | ((unsigned)b << 16);
}

// K1: fused LN + q/k + mlp1 (blocks 0..511) + T-sum of tij (blocks 512..639).
__global__ __launch_bounds__(256) void k_front(
    const float* __restrict__ h, const float* __restrict__ ghi, const float* __restrict__ ghj,
    const float* __restrict__ Wq, const float* __restrict__ Wk,
    const float* __restrict__ Wv1, const float* __restrict__ bv1,
    const float* __restrict__ Wp1, const float* __restrict__ bp1,
    const float* __restrict__ tij,
    float* __restrict__ q, float* __restrict__ k,
    float* __restrict__ a1, float* __restrict__ p1, float* __restrict__ T) {
    int b = blockIdx.x, t = threadIdx.x;
    if (b >= 512) {
        // ---- T[i][c] = sum_j tij[i][j][c]
        int i = b - 512;
        __shared__ float red[4][64];
        int c = t & 63, jg = t >> 6;
        float s = 0.f;
        for (int j = jg; j < NN; j += 4) s += tij[(size_t)(i * NN + j) * DD_ + c];
        red[jg][c] = s;
        __syncthreads();
        if (t < 64) T[i * 64 + t] = red[0][t] + red[1][t] + red[2][t] + red[3][t];
        return;
    }
    int i = b & 127, ch = b >> 7;
    int d = t & 63;
    __shared__ float hib[DD_], hjb[DD_];
    float x = h[i * DD_ + d];
    float s = wave_sum64(x);
    float s2 = wave_sum64(x * x);
    float m = s * (1.0f / DD_);
    float v = s2 * (1.0f / DD_) - m * m;
    float r = rsqrtf(v + 1e-5f);
    float xc = (x - m) * r;
    if (t < 64) { hib[d] = xc * ghi[d]; hjb[d] = xc * ghj[d]; }
    __syncthreads();
    {
        int c = ch * 128 + (t & 127);
        const float* W = (t < 128) ? Wq : Wk;
        const float* hb = (t < 128) ? hib : hjb;
        float a = 0.f;
#pragma unroll 8
        for (int dd = 0; dd < DD_; dd++) a += hb[dd] * W[dd * DI_ + c];
        float* dstqk = (t < 128) ? q : k;
        dstqk[i * DI_ + c] = a;
    }
    {
        int c = ch * 256 + t;
        float av = 0.f, ap = 0.f;
#pragma unroll 4
        for (int dd = 0; dd < DD_; dd++) {
            float hv = hjb[dd];
            av += hv * Wv1[dd * MLPD + c];
            ap += hv * Wp1[dd * MLPD + c];
        }
        float xv = av + bv1[c], xp = ap + bp1[c];
        a1[i * MLPD + c] = xv / (1.0f + expf(-xv));
        p1[i * MLPD + c] = xp / (1.0f + expf(-xp));
    }
}

// K_mid: fused mlp2 (blocks 0..319) + den (320..959, 128 i x 5 chunks) +
// simnum (960..1471). All depend only on k_front; one launch, concurrent.
__global__ __launch_bounds__(256) void k_mid(
    const float* __restrict__ a1, const float* __restrict__ p1,
    const float* __restrict__ Wv2, const float* __restrict__ Wp2,
    float* __restrict__ part,
    const float* __restrict__ T, const float* __restrict__ Wev,
    const float* __restrict__ q, float* __restrict__ rsd,
    const float* __restrict__ k, float* __restrict__ sn) {
    __shared__ __align__(16) unsigned char smem[30720];
    int b = blockIdx.x, t = threadIdx.x;
    if (b < 320) {
        // ---- mlp2: split-K MFMA GEMM (hi/lo bf16 compensation)
        unsigned short (*Ahi)[40] = (unsigned short (*)[40])(smem);
        unsigned short (*Alo)[40] = (unsigned short (*)[40])(smem + 10240);
        unsigned short (*Bhi)[40] = (unsigned short (*)[40])(smem + 20480);
        unsigned short (*Blo)[40] = (unsigned short (*)[40])(smem + 25600);
        int ct = b % 80, ks = b / 80;
        int c0 = ct * 64;
        bool isp = c0 >= 2560;
        int c0l = c0 - (isp ? 2560 : 0);
        const float* __restrict__ src = isp ? p1 : a1;
        const float* __restrict__ W = isp ? Wp2 : Wv2;
        int kbase = ks * 256;
        int lane = t & 63, wv = t >> 6;
        int l15 = lane & 15, quad = lane >> 4;
        f32x4 acc[2][4];
#pragma unroll
        for (int mt = 0; mt < 2; mt++)
#pragma unroll
            for (int nt = 0; nt < 4; nt++) acc[mt][nt] = (f32x4){0.f, 0.f, 0.f, 0.f};
        int aj = t >> 1, ak = (t & 1) * 16;
        int bc = t & 63, bk = (t >> 6) * 8;
        for (int kc = 0; kc < 8; kc++) {
            int k0 = kbase + kc * 32;
            __syncthreads();
            {
                unsigned short h16[16], l16[16];
                const float* ap = &src[(size_t)aj * MLPD + k0 + ak];
#pragma unroll
                for (int e = 0; e < 16; e += 4) {
                    float4 v = *(const float4*)(ap + e);
                    float vv[4] = {v.x, v.y, v.z, v.w};
#pragma unroll
                    for (int z = 0; z < 4; z++) {
                        unsigned short hb = f2bf_u(vv[z]);
                        h16[e + z] = hb;
                        l16[e + z] = f2bf_u(vv[z] - bfu2f(hb));
                    }
                }
                *(uint4*)&Ahi[aj][ak] = make_uint4(pk2(h16[0], h16[1]), pk2(h16[2], h16[3]),
                                                   pk2(h16[4], h16[5]), pk2(h16[6], h16[7]));
                *(uint4*)&Ahi[aj][ak + 8] = make_uint4(pk2(h16[8], h16[9]), pk2(h16[10], h16[11]),
                                                       pk2(h16[12], h16[13]), pk2(h16[14], h16[15]));
                *(uint4*)&Alo[aj][ak] = make_uint4(pk2(l16[0], l16[1]), pk2(l16[2], l16[3]),
                                                   pk2(l16[4], l16[5]), pk2(l16[6], l16[7]));
                *(uint4*)&Alo[aj][ak + 8] = make_uint4(pk2(l16[8], l16[9]), pk2(l16[10], l16[11]),
                                                       pk2(l16[12], l16[13]), pk2(l16[14], l16[15]));
            }
            {
                unsigned short h8[8], l8[8];
#pragma unroll
                for (int e = 0; e < 8; e++) {
                    float v = W[(size_t)(k0 + bk + e) * SDI + c0l + bc];
                    unsigned short hb = f2bf_u(v);
                    h8[e] = hb;
                    l8[e] = f2bf_u(v - bfu2f(hb));
                }
                *(uint4*)&Bhi[bc][bk] = make_uint4(pk2(h8[0], h8[1]), pk2(h8[2], h8[3]),
                                                   pk2(h8[4], h8[5]), pk2(h8[6], h8[7]));
                *(uint4*)&Blo[bc][bk] = make_uint4(pk2(l8[0], l8[1]), pk2(l8[2], l8[3]),
                                                   pk2(l8[4], l8[5]), pk2(l8[6], l8[7]));
            }
            __syncthreads();
            int ko = quad * 8;
            short8 a_h0 = *(const short8*)&Ahi[(wv * 2 + 0) * 16 + l15][ko];
            short8 a_l0 = *(const short8*)&Alo[(wv * 2 + 0) * 16 + l15][ko];
            short8 a_h1 = *(const short8*)&Ahi[(wv * 2 + 1) * 16 + l15][ko];
            short8 a_l1 = *(const short8*)&Alo[(wv * 2 + 1) * 16 + l15][ko];
#pragma unroll
            for (int nt = 0; nt < 4; nt++) {
                short8 b_h = *(const short8*)&Bhi[nt * 16 + l15][ko];
                short8 b_l = *(const short8*)&Blo[nt * 16 + l15][ko];
                acc[0][nt] = __builtin_amdgcn_mfma_f32_16x16x32_bf16(a_h0, b_h, acc[0][nt], 0, 0, 0);
                acc[0][nt] = __builtin_amdgcn_mfma_f32_16x16x32_bf16(a_h0, b_l, acc[0][nt], 0, 0, 0);
                acc[0][nt] = __builtin_amdgcn_mfma_f32_16x16x32_bf16(a_l0, b_h, acc[0][nt], 0, 0, 0);
                acc[1][nt] = __builtin_amdgcn_mfma_f32_16x16x32_bf16(a_h1, b_h, acc[1][nt], 0, 0, 0);
                acc[1][nt] = __builtin_amdgcn_mfma_f32_16x16x32_bf16(a_h1, b_l, acc[1][nt], 0, 0, 0);
                acc[1][nt] = __builtin_amdgcn_mfma_f32_16x16x32_bf16(a_l1, b_h, acc[1][nt], 0, 0, 0);
            }
        }
#pragma unroll
        for (int mt = 0; mt < 2; mt++)
#pragma unroll
            for (int nt = 0; nt < 4; nt++)
#pragma unroll
                for (int r = 0; r < 4; r++) {
                    int j = (wv * 2 + mt) * 16 + quad * 4 + r;
                    int cc = c0 + nt * 16 + l15;
                    part[(size_t)ks * 655360 + (size_t)j * 5120 + cc] = acc[mt][nt][r];
                }
    } else if (b < 960) {
        // ---- den: EV dot + rsd. 128 i x 5 u-chunks, 512 cols/block.
        float* Tl = (float*)smem;          // 64
        float* ql = (float*)(smem + 256);  // 512
        int idx = b - 320;
        int i = idx & 127, chunk = idx >> 7;
        if (t < 64) Tl[t] = T[i * 64 + t];
        ql[t] = q[i * DI_ + t];
        ql[t + 256] = q[i * DI_ + t + 256];
        __syncthreads();
#pragma unroll
        for (int kx = 0; kx < 2; kx++) {
            int u = chunk * 512 + kx * 256 + t;
            float ev = 0.f;
#pragma unroll 8
            for (int cc = 0; cc < DD_; cc++) ev += Tl[cc] * Wev[(size_t)cc * SDI + u];
            float den = wave_sum64(ev * ql[u & 511]);
            if ((t & 63) == 0) {
                int g = u >> 6;
                int ss = g >> 3, hh = g & 7;
                rsd[i * 40 + hh * SS_ + ss] = 1.0f / den;
            }
        }
    } else {
        // ---- simnum: 2 heads per block (256 threads)
        float* qb = (float*)smem;  // 128
        int idx = b - 960;
        int i = idx & 127, yh = idx >> 7;
        if (t < 128) qb[t] = q[i * DI_ + yh * 128 + t];
        __syncthreads();
        int hh = yh * 2 + (t >> 7), j = t & 127;
        float a = 0.f;
        const float* kr = &k[(size_t)j * DI_ + hh * DH_];
        const float* qr = &qb[(t >> 7) * 64];
#pragma unroll 8
        for (int d = 0; d < DH_; d++) a += qr[d] * kr[d];
        sn[i * 1024 + hh * NN + j] = a;
    }
}

// K_mid2: fused VC (blocks 0..639) + M (640..1279) + dst init (1280..1315).
__global__ __launch_bounds__(256) void k_mid2(
    const float* __restrict__ part, const float* __restrict__ bv2,
    const float* __restrict__ bp2, const float* __restrict__ Wc,
    const float* __restrict__ Wev, float* __restrict__ VC, float* __restrict__ M,
    const float* __restrict__ h, float* __restrict__ dst) {
    __shared__ __align__(16) unsigned char smem[38912];
    int b = blockIdx.x, t = threadIdx.x;
    if (b >= 1280) {
        // ---- dst init: h for scalar slot, 0 for moment slots (73728 floats).
        int idx = b - 1280;
#pragma unroll
        for (int r = 0; r < 8; r++) {
            int u = idx * 2048 + r * 256 + t;
            dst[u] = (u < 8192) ? h[u] : 0.f;
        }
        return;
    }
    if (b < 640) {
        float* vlds = (float*)smem;  // 512
        int j = b & 127, s = b >> 7;
#pragma unroll
        for (int r = 0; r < 2; r++) {
            int tt = r * 256 + t;
            int e = s * 512 + tt;
            float sum = 0.f;
#pragma unroll
            for (int p = 0; p < KS2; p++) sum += part[(size_t)p * 655360 + (size_t)j * 5120 + e];
            vlds[tt] = sum + bv2[e];
        }
        __syncthreads();
#pragma unroll
        for (int r = 0; r < 2; r++) {
            int tt = r * 256 + t;
            int dd = tt & 63;
            int hbase = tt - dd;
            float acc = 0.f;
#pragma unroll 8
            for (int d2 = 0; d2 < DH_; d2++)
                acc += vlds[hbase + d2] * Wc[(size_t)(hbase + d2) * DD_ + dd];
            VC[(size_t)(j * SS_ + s) * DI_ + tt] = acc;
        }
    } else {
        int idx = b - 640;
        int j = idx & 127, s = idx >> 7;
        int lane = t & 63, w = t >> 6;
        float* P = (float*)smem;  // 512 floats
        unsigned short (*Ahi)[72] = (unsigned short (*)[72])(smem + 2048);
        unsigned short (*Alo)[72] = (unsigned short (*)[72])(smem + 11264);
        unsigned short (*Bhi)[72] = (unsigned short (*)[72])(smem + 20480);
        unsigned short (*Blo)[72] = (unsigned short (*)[72])(smem + 29696);
        {
            int e = 2560 + s * 512 + t;
            float s0 = 0.f, s1 = 0.f;
#pragma unroll
            for (int p = 0; p < KS2; p++) {
                s0 += part[(size_t)p * 655360 + (size_t)j * 5120 + e];
                s1 += part[(size_t)p * 655360 + (size_t)j * 5120 + e + 256];
            }
            P[t] = s0 + bp2[s * 512 + t];
            P[t + 256] = s1 + bp2[s * 512 + t + 256];
        }
        f32x4 acc[4];
#pragma unroll
        for (int n = 0; n < 4; n++) acc[n] = (f32x4){0.f, 0.f, 0.f, 0.f};
        __syncthreads();
        for (int u0 = 0; u0 < DI_; u0 += KCM) {
            {
                int c = t >> 2, ug = (t & 3) * 16;
                const float* wevp = &Wev[(size_t)c * SDI + s * DI_ + u0 + ug];
                unsigned short ah[16], al[16];
#pragma unroll
                for (int e = 0; e < 16; e += 4) {
                    float4 wv = *(const float4*)(wevp + e);
                    float4 pv = *(const float4*)&P[u0 + ug + e];
                    float av[4] = {wv.x * pv.x, wv.y * pv.y, wv.z * pv.z, wv.w * pv.w};
#pragma unroll
                    for (int z = 0; z < 4; z++) {
                        unsigned short hh2 = f2bf_u(av[z]);
                        ah[e + z] = hh2;
                        al[e + z] = f2bf_u(av[z] - bfu2f(hh2));
                    }
                }
                *(uint4*)&Ahi[c][ug] = make_uint4(pk2(ah[0], ah[1]), pk2(ah[2], ah[3]),
                                                  pk2(ah[4], ah[5]), pk2(ah[6], ah[7]));
                *(uint4*)&Ahi[c][ug + 8] = make_uint4(pk2(ah[8], ah[9]), pk2(ah[10], ah[11]),
                                                      pk2(ah[12], ah[13]), pk2(ah[14], ah[15]));
                *(uint4*)&Alo[c][ug] = make_uint4(pk2(al[0], al[1]), pk2(al[2], al[3]),
                                                  pk2(al[4], al[5]), pk2(al[6], al[7]));
                *(uint4*)&Alo[c][ug + 8] = make_uint4(pk2(al[8], al[9]), pk2(al[10], al[11]),
                                                      pk2(al[12], al[13]), pk2(al[14], al[15]));
            }
            {
                int dd = t & 63, ub = (t >> 6) * 16;
                unsigned short bh[16], bl[16];
#pragma unroll
                for (int e = 0; e < 16; e++) {
                    float v = Wc[(size_t)(u0 + ub + e) * DD_ + dd];
                    unsigned short hh2 = f2bf_u(v);
                    bh[e] = hh2;
                    bl[e] = f2bf_u(v - bfu2f(hh2));
                }
                *(uint4*)&Bhi[dd][ub] = make_uint4(pk2(bh[0], bh[1]), pk2(bh[2], bh[3]),
                                                   pk2(bh[4], bh[5]), pk2(bh[6], bh[7]));
                *(uint4*)&Bhi[dd][ub + 8] = make_uint4(pk2(bh[8], bh[9]), pk2(bh[10], bh[11]),
                                                       pk2(bh[12], bh[13]), pk2(bh[14], bh[15]));
                *(uint4*)&Blo[dd][ub] = make_uint4(pk2(bl[0], bl[1]), pk2(bl[2], bl[3]),
                                                   pk2(bl[4], bl[5]), pk2(bl[6], bl[7]));
                *(uint4*)&Blo[dd][ub + 8] = make_uint4(pk2(bl[8], bl[9]), pk2(bl[10], bl[11]),
                                                       pk2(bl[12], bl[13]), pk2(bl[14], bl[15]));
            }
            __syncthreads();
#pragma unroll
            for (int kk = 0; kk < 2; kk++) {
                int ko = kk * 32 + (lane >> 4) * 8;
                short8 a_h = *(const short8*)&Ahi[w * 16 + (lane & 15)][ko];
                short8 a_l = *(const short8*)&Alo[w * 16 + (lane & 15)][ko];
#pragma unroll
                for (int n = 0; n < 4; n++) {
                    short8 b_h = *(const short8*)&Bhi[n * 16 + (lane & 15)][ko];
                    short8 b_l = *(const short8*)&Blo[n * 16 + (lane & 15)][ko];
                    acc[n] = __builtin_amdgcn_mfma_f32_16x16x32_bf16(a_h, b_h, acc[n], 0, 0, 0);
                    acc[n] = __builtin_amdgcn_mfma_f32_16x16x32_bf16(a_h, b_l, acc[n], 0, 0, 0);
                    acc[n] = __builtin_amdgcn_mfma_f32_16x16x32_bf16(a_l, b_h, acc[n], 0, 0, 0);
                }
            }
            __syncthreads();
        }
        float* Mp = &M[(size_t)(j * SS_ + s) * 4096];
#pragma unroll
        for (int n = 0; n < 4; n++)
#pragma unroll
            for (int r = 0; r < 4; r++) {
                int c = w * 16 + (lane >> 4) * 4 + r;
                int dd = n * 16 + (lane & 15);
                Mp[c * 64 + dd] = acc[n][r];
            }
    }
}

// K10: out = (t_ij @ M) + (snr @ VC) via MFMA (hi/lo comp). grid(128 j, 5 s), block(256).
__global__ __launch_bounds__(256) void k_out(const float* __restrict__ M, const float* __restrict__ VC,
                                             const float* __restrict__ sn, const float* __restrict__ rsd,
                                             const float* __restrict__ tij, float* __restrict__ outb) {
    int j = blockIdx.x, s = blockIdx.y, t = threadIdx.x;
    int lane = t & 63, wv = t >> 6, l15 = lane & 15, quad = lane >> 4;
    __shared__ unsigned short Ahi[128][40], Alo[128][40];
    __shared__ unsigned short Bhi[64][40], Blo[64][40];
    f32x4 acc[2][4];
#pragma unroll
    for (int mt = 0; mt < 2; mt++)
#pragma unroll
        for (int nt = 0; nt < 4; nt++) acc[mt][nt] = (f32x4){0.f, 0.f, 0.f, 0.f};
    {
        int i = t >> 1, hg = (t & 1) * 4;
        unsigned short h4[4], l4[4];
#pragma unroll
        for (int e = 0; e < 4; e++) {
            int hh_ = hg + e;
            float v = sn[i * 1024 + hh_ * NN + j] * rsd[i * 40 + hh_ * SS_ + s];
            unsigned short hb = f2bf_u(v);
            h4[e] = hb;
            l4[e] = f2bf_u(v - bfu2f(hb));
        }
        *(uint2*)&Ahi[i][hg] = make_uint2(pk2(h4[0], h4[1]), pk2(h4[2], h4[3]));
        *(uint2*)&Alo[i][hg] = make_uint2(pk2(l4[0], l4[1]), pk2(l4[2], l4[3]));
#pragma unroll
        for (int r = 0; r < 2; r++) {
            int idx = t + r * 256;
            if (idx < 384) {
                int ii = idx / 3, g = idx % 3;
                *(uint4*)&Ahi[ii][8 + g * 8] = make_uint4(0, 0, 0, 0);
                *(uint4*)&Alo[ii][8 + g * 8] = make_uint4(0, 0, 0, 0);
            }
        }
        if (t < 64) {
            unsigned short h8[8], l8[8];
#pragma unroll
            for (int e = 0; e < 8; e++) {
                float v = VC[(size_t)(j * SS_ + s) * DI_ + e * 64 + t];
                unsigned short hb = f2bf_u(v);
                h8[e] = hb;
                l8[e] = f2bf_u(v - bfu2f(hb));
            }
            *(uint4*)&Bhi[t][0] = make_uint4(pk2(h8[0], h8[1]), pk2(h8[2], h8[3]),
                                             pk2(h8[4], h8[5]), pk2(h8[6], h8[7]));
            *(uint4*)&Blo[t][0] = make_uint4(pk2(l8[0], l8[1]), pk2(l8[2], l8[3]),
                                             pk2(l8[4], l8[5]), pk2(l8[6], l8[7]));
        } else {
            int idx = t - 64;
            int dd2 = idx / 3, g = idx % 3;
            *(uint4*)&Bhi[dd2][8 + g * 8] = make_uint4(0, 0, 0, 0);
            *(uint4*)&Blo[dd2][8 + g * 8] = make_uint4(0, 0, 0, 0);
        }
    }
    __syncthreads();
    {
        int ko = quad * 8;
        short8 a_h0 = *(const short8*)&Ahi[(wv * 2 + 0) * 16 + l15][ko];
        short8 a_l0 = *(const short8*)&Alo[(wv * 2 + 0) * 16 + l15][ko];
        short8 a_h1 = *(const short8*)&Ahi[(wv * 2 + 1) * 16 + l15][ko];
        short8 a_l1 = *(const short8*)&Alo[(wv * 2 + 1) * 16 + l15][ko];
#pragma unroll
        for (int nt = 0; nt < 4; nt++) {
            short8 b_h = *(const short8*)&Bhi[nt * 16 + l15][ko];
            short8 b_l = *(const short8*)&Blo[nt * 16 + l15][ko];
            acc[0][nt] = __builtin_amdgcn_mfma_f32_16x16x32_bf16(a_h0, b_h, acc[0][nt], 0, 0, 0);
            acc[0][nt] = __builtin_amdgcn_mfma_f32_16x16x32_bf16(a_h0, b_l, acc[0][nt], 0, 0, 0);
            acc[0][nt] = __builtin_amdgcn_mfma_f32_16x16x32_bf16(a_l0, b_h, acc[0][nt], 0, 0, 0);
            acc[1][nt] = __builtin_amdgcn_mfma_f32_16x16x32_bf16(a_h1, b_h, acc[1][nt], 0, 0, 0);
            acc[1][nt] = __builtin_amdgcn_mfma_f32_16x16x32_bf16(a_h1, b_l, acc[1][nt], 0, 0, 0);
            acc[1][nt] = __builtin_amdgcn_mfma_f32_16x16x32_bf16(a_l1, b_h, acc[1][nt], 0, 0, 0);
        }
    }
    for (int kc = 0; kc < 2; kc++) {
        __syncthreads();
        {
            int i = t >> 1, chalf = (t & 1) * 16;
            unsigned short h16[16], l16[16];
            const float* tp = &tij[(size_t)(i * NN + j) * DD_ + kc * 32 + chalf];
#pragma unroll
            for (int e = 0; e < 16; e += 4) {
                float4 v = *(const float4*)(tp + e);
                float vv[4] = {v.x, v.y, v.z, v.w};
#pragma unroll
                for (int z = 0; z < 4; z++) {
                    unsigned short hb = f2bf_u(vv[z]);
                    h16[e + z] = hb;
                    l16[e + z] = f2bf_u(vv[z] - bfu2f(hb));
                }
            }
            *(uint4*)&Ahi[i][chalf] = make_uint4(pk2(h16[0], h16[1]), pk2(h16[2], h16[3]),
                                                 pk2(h16[4], h16[5]), pk2(h16[6], h16[7]));
            *(uint4*)&Ahi[i][chalf + 8] = make_uint4(pk2(h16[8], h16[9]), pk2(h16[10], h16[11]),
                                                     pk2(h16[12], h16[13]), pk2(h16[14], h16[15]));
            *(uint4*)&Alo[i][chalf] = make_uint4(pk2(l16[0], l16[1]), pk2(l16[2], l16[3]),
                                                 pk2(l16[4], l16[5]), pk2(l16[6], l16[7]));
            *(uint4*)&Alo[i][chalf + 8] = make_uint4(pk2(l16[8], l16[9]), pk2(l16[10], l16[11]),
                                                     pk2(l16[12], l16[13]), pk2(l16[14], l16[15]));
        }
        {
            int dd2 = t & 63, cg = (t >> 6) * 8;
            unsigned short h8[8], l8[8];
#pragma unroll
            for (int e = 0; e < 8; e++) {
                float v = M[(size_t)(j * SS_ + s) * 4096 + (size_t)(kc * 32 + cg + e) * 64 + dd2];
                unsigned short hb = f2bf_u(v);
                h8[e] = hb;
                l8[e] = f2bf_u(v - bfu2f(hb));
            }
            *(uint4*)&Bhi[dd2][cg] = make_uint4(pk2(h8[0], h8[1]), pk2(h8[2], h8[3]),
                                                pk2(h8[4], h8[5]), pk2(h8[6], h8[7]));
            *(uint4*)&Blo[dd2][cg] = make_uint4(pk2(l8[0], l8[1]), pk2(l8[2], l8[3]),
                                                pk2(l8[4], l8[5]), pk2(l8[6], l8[7]));
        }
        __syncthreads();
        int ko = quad * 8;
        short8 a_h0 = *(const short8*)&Ahi[(wv * 2 + 0) * 16 + l15][ko];
        short8 a_l0 = *(const short8*)&Alo[(wv * 2 + 0) * 16 + l15][ko];
        short8 a_h1 = *(const short8*)&Ahi[(wv * 2 + 1) * 16 + l15][ko];
        short8 a_l1 = *(const short8*)&Alo[(wv * 2 + 1) * 16 + l15][ko];
#pragma unroll
        for (int nt = 0; nt < 4; nt++) {
            short8 b_h = *(const short8*)&Bhi[nt * 16 + l15][ko];
            short8 b_l = *(const short8*)&Blo[nt * 16 + l15][ko];
            acc[0][nt] = __builtin_amdgcn_mfma_f32_16x16x32_bf16(a_h0, b_h, acc[0][nt], 0, 0, 0);
            acc[0][nt] = __builtin_amdgcn_mfma_f32_16x16x32_bf16(a_h0, b_l, acc[0][nt], 0, 0, 0);
            acc[0][nt] = __builtin_amdgcn_mfma_f32_16x16x32_bf16(a_l0, b_h, acc[0][nt], 0, 0, 0);
            acc[1][nt] = __builtin_amdgcn_mfma_f32_16x16x32_bf16(a_h1, b_h, acc[1][nt], 0, 0, 0);
            acc[1][nt] = __builtin_amdgcn_mfma_f32_16x16x32_bf16(a_h1, b_l, acc[1][nt], 0, 0, 0);
            acc[1][nt] = __builtin_amdgcn_mfma_f32_16x16x32_bf16(a_l1, b_h, acc[1][nt], 0, 0, 0);
        }
    }
#pragma unroll
    for (int mt = 0; mt < 2; mt++)
#pragma unroll
        for (int nt = 0; nt < 4; nt++)
#pragma unroll
            for (int r = 0; r < 4; r++) {
                int i = (wv * 2 + mt) * 16 + quad * 4 + r;
                int dd = nt * 16 + l15;
                outb[((size_t)(i * NN + j) * SS_ + s) * 64 + dd] = acc[mt][nt][r];
            }
}

// K_redF: parallel j-reduction with atomic combine into pre-initialized dst.
// grid(128 i, 8 jc), block(320): 16 j per block.
__global__ __launch_bounds__(320) void k_redF(const float* __restrict__ outb,
                                              const float* __restrict__ r1, const float* __restrict__ r2,
                                              const float* __restrict__ x1, const float* __restrict__ x2,
                                              float* __restrict__ dst) {
    int i = blockIdx.x, jc = blockIdx.y, t = threadIdx.x;
    int s = t >> 6, dd = t & 63;
    float am[5] = {0.f, 0.f, 0.f, 0.f, 0.f};
    int jbeg = jc * 16;
    for (int jj = 0; jj < 16; jj++) {
        int j = jbeg + jj;
        float ov = outb[((size_t)(i * NN + j) * SS_ + s) * 64 + dd];
        if (s == 0) {
            am[0] += ov;
        } else if (s == 1) {
#pragma unroll
            for (int m = 0; m < 3; m++) am[m] += r1[(i * NN + j) * 3 + m] * ov;
        } else if (s == 2) {
#pragma unroll
            for (int m = 0; m < 5; m++) am[m] += r2[(i * NN + j) * 5 + m] * ov;
        } else if (s == 3) {
#pragma unroll
            for (int m = 0; m < 3; m++) am[m] += x1[(j * DD_ + dd) * 3 + m] * ov;
        } else {
#pragma unroll
            for (int m = 0; m < 5; m++) am[m] += x2[(j * DD_ + dd) * 5 + m] * ov;
        }
    }
    if (s == 0) {
        atomicAdd(&dst[i * DD_ + dd], am[0]);
    } else if (s == 1 || s == 3) {
#pragma unroll
        for (int m = 0; m < 3; m++) atomicAdd(&dst[8192 + (i * DD_ + dd) * 3 + m], am[m]);
    } else {
#pragma unroll
        for (int m = 0; m < 5; m++) atomicAdd(&dst[8192 + 24576 + (i * DD_ + dd) * 5 + m], am[m]);
    }
}

extern "C" void kernel_launch(void* const* d_in, const int* in_sizes, int n_in,
                              void* d_out, int out_size, void* d_ws, size_t ws_size,
                              hipStream_t stream) {
    const float* h_in = (const float*)d_in[0];
    const float* tij = (const float*)d_in[1];
    const float* r1 = (const float*)d_in[2];
    const float* r2 = (const float*)d_in[3];
    const float* x1 = (const float*)d_in[4];
    const float* x2 = (const float*)d_in[5];
    const float* ghi = (const float*)d_in[6];
    const float* ghj = (const float*)d_in[7];
    const float* Wq = (const float*)d_in[8];
    const float* Wk = (const float*)d_in[9];
    const float* Wv1 = (const float*)d_in[10];
    const float* bv1 = (const float*)d_in[11];
    const float* Wv2 = (const float*)d_in[12];
    const float* bv2 = (const float*)d_in[13];
    const float* Wp1 = (const float*)d_in[14];
    const float* bp1 = (const float*)d_in[15];
    const float* Wp2 = (const float*)d_in[16];
    const float* bp2 = (const float*)d_in[17];
    const float* Wev = (const float*)d_in[18];
    const float* Wc = (const float*)d_in[19];
    float* dst = (float*)d_out;

    float* w = (float*)d_ws;
    size_t off = 16;
    auto alloc = [&](size_t n) { float* p = w + off; off += n; return p; };
    float* q    = alloc(65536);
    float* k    = alloc(65536);
    float* a1   = alloc(131072);
    float* p1   = alloc(131072);
    float* VC   = alloc(327680);
    float* sn   = alloc(131072);
    float* rsd  = alloc(5120);
    float* M    = alloc(2621440);
    float* outb = alloc(5242880);
    float* part = alloc(2621440);   // 4 x 655360 split-K partials
    float* T    = alloc(8192);      // 128 x 64 j-summed t_ij

    k_front<<<dim3(640), dim3(256), 0, stream>>>(h_in, ghi, ghj, Wq, Wk, Wv1, bv1, Wp1, bp1,
                                                 tij, q, k, a1, p1, T);
    k_mid<<<dim3(1472), dim3(256), 0, stream>>>(a1, p1, Wv2, Wp2, part, T, Wev, q, rsd, k, sn);
    k_mid2<<<dim3(1316), dim3(256), 0, stream>>>(part, bv2, bp2, Wc, Wev, VC, M, h_in, dst);
    k_out<<<dim3(128, 5), dim3(256), 0, stream>>>(M, VC, sn, rsd, tij, outb);
    k_redF<<<dim3(128, 8), dim3(320), 0, stream>>>(outb, r1, r2, x1, x2, dst);
}